// Round 6
// baseline (167.904 us; speedup 1.0000x reference)
//
#include <hip/hip_runtime.h>
#include <hip/hip_bf16.h>
#include <math.h>

// Problem constants: N=3072 nodes, F=128 in-feats, H=16 hidden, O=8 out
#define NN 3072
#define FF 128
#define HH 16
#define OO 8

#define MC   1024              // m-chunk per block
#define NCH  3                 // NN / MC
#define RPB  8                 // rows per block (one per wave), 512 threads

// ws layout (float offsets): gT[O][N] only
#define OFF_GT   0

// ---------------------------------------------------------------------------
// Kernel 1: gT[o][n] = sum_f ( sum_h relu(x[n,f]*W1[f,h]+b1[f,h]) * W2[f,h,o]
//                              + b2[f,o] )
// Thread = feature, weights streamed per-h. Also zeroes `out` (first 48
// blocks) so no separate memset dispatch is needed (stream order guarantees
// completion before gnan_main_kernel starts).
// ---------------------------------------------------------------------------
#define NPB 4

__global__ __launch_bounds__(128) void gnan_g_kernel(
    const float* __restrict__ x,    // [N,F]
    const float* __restrict__ W1,   // [F,H]
    const float* __restrict__ b1,   // [F,H]
    const float* __restrict__ W2,   // [F,H,O]
    const float* __restrict__ b2,   // [F,O]
    float* __restrict__ gT,         // [O][N] in ws
    float* __restrict__ out)        // [N,O] zeroed here
{
    const int f  = threadIdx.x;
    const int n0 = blockIdx.x * NPB;

    // zero out[] : NN*OO floats = 6144 float4, one per thread of blocks 0..47
    {
        const int gid = blockIdx.x * 128 + threadIdx.x;
        if (gid < NN * OO / 4)
            reinterpret_cast<float4*>(out)[gid] = make_float4(0.f, 0.f, 0.f, 0.f);
    }

    float xv[NPB];
#pragma unroll
    for (int ni = 0; ni < NPB; ++ni)
        xv[ni] = x[(size_t)(n0 + ni) * FF + f];

    const float4 b2a = *reinterpret_cast<const float4*>(b2 + f * OO);
    const float4 b2b = *reinterpret_cast<const float4*>(b2 + f * OO + 4);

    float acc[NPB][OO];
#pragma unroll
    for (int ni = 0; ni < NPB; ++ni) {
        acc[ni][0] = b2a.x; acc[ni][1] = b2a.y; acc[ni][2] = b2a.z; acc[ni][3] = b2a.w;
        acc[ni][4] = b2b.x; acc[ni][5] = b2b.y; acc[ni][6] = b2b.z; acc[ni][7] = b2b.w;
    }

    for (int h = 0; h < HH; ++h) {
        const float w1h = W1[f * HH + h];
        const float b1h = b1[f * HH + h];
        const float4 wa = *reinterpret_cast<const float4*>(W2 + (size_t)(f * HH + h) * OO);
        const float4 wb = *reinterpret_cast<const float4*>(W2 + (size_t)(f * HH + h) * OO + 4);
#pragma unroll
        for (int ni = 0; ni < NPB; ++ni) {
            const float a = fmaxf(fmaf(xv[ni], w1h, b1h), 0.f);
            acc[ni][0] = fmaf(a, wa.x, acc[ni][0]);
            acc[ni][1] = fmaf(a, wa.y, acc[ni][1]);
            acc[ni][2] = fmaf(a, wa.z, acc[ni][2]);
            acc[ni][3] = fmaf(a, wa.w, acc[ni][3]);
            acc[ni][4] = fmaf(a, wb.x, acc[ni][4]);
            acc[ni][5] = fmaf(a, wb.y, acc[ni][5]);
            acc[ni][6] = fmaf(a, wb.z, acc[ni][6]);
            acc[ni][7] = fmaf(a, wb.w, acc[ni][7]);
        }
    }

    // reduce all NPB nodes, ONE barrier, 32 threads write
    __shared__ float wsum[NPB][2][OO];
    const int lane = threadIdx.x & 63;
    const int wid  = threadIdx.x >> 6;
#pragma unroll
    for (int ni = 0; ni < NPB; ++ni) {
#pragma unroll
        for (int o = 0; o < OO; ++o) {
#pragma unroll
            for (int off = 32; off > 0; off >>= 1)
                acc[ni][o] += __shfl_down(acc[ni][o], off);
        }
        if (lane == 0) {
#pragma unroll
            for (int o = 0; o < OO; ++o) wsum[ni][wid][o] = acc[ni][o];
        }
    }
    __syncthreads();
    if (threadIdx.x < NPB * OO) {
        const int ni = threadIdx.x >> 3, o = threadIdx.x & 7;
        gT[o * NN + (n0 + ni)] = wsum[ni][0][o] + wsum[ni][1][o];
    }
}

// ---------------------------------------------------------------------------
// Miss-path correction (rare): exact per-interval alpha/beta vs reference.
// LDS arrays may be runtime-indexed (rule #20 applies to register arrays).
// ---------------------------------------------------------------------------
__device__ __forceinline__ void accum_one(
    float d, float clo, float chi, const float gk[OO],
    float dg[OO], float corr[OO],
    const float* KpS, const float (*rowsS)[16], const float* refB)
{
    if (d >= clo && d < chi) {               // reference interval (hot)
#pragma unroll
        for (int o = 0; o < OO; ++o) dg[o] = fmaf(d, gk[o], dg[o]);
    } else {                                 // rare exact correction
        int j = 0;
#pragma unroll
        for (int p = 0; p < HH; ++p) j += (d >= KpS[1 + p]) ? 1 : 0;
#pragma unroll
        for (int o = 0; o < OO; ++o) {
            const float v = fmaf(rowsS[j][o], d, rowsS[j][8 + o]) - refB[o];
            corr[o] = fmaf(v, gk[o], corr[o]);
        }
    }
}

// ---------------------------------------------------------------------------
// Kernel 2 (main): out[n,o] += alpha_ref[o]*sum_m d*g + beta_ref[o]*sum_m g
//                              + corrections.
// Self-contained: rank-based interval tables built per-block in LDS (no
// setup kernel, no ws table dependency). Block = 512 thr = 8 waves = 8 rows
// x one 1024-m chunk; gs = 32 KB; ~4 blocks/CU (wave-limited).
// ---------------------------------------------------------------------------
__global__ __launch_bounds__(512) void gnan_main_kernel(
    const float* __restrict__ nd,    // [N,N]
    const float* __restrict__ nm,    // [N,N]
    const float* __restrict__ wsf,   // ws: gT
    const float* __restrict__ rW1,   // [H]
    const float* __restrict__ rb1,   // [H]
    const float* __restrict__ rW2,   // [H,O]
    const float* __restrict__ rb2,   // [O]
    float* __restrict__ out)         // [N,O], zeroed by g-kernel
{
    __shared__ float gs[OO * MC];    // 32 KB
    __shared__ float gsum[OO];
    __shared__ float KpS[HH + 2];
    __shared__ float rowsS[HH + 1][16];
    __shared__ float refS[18];       // clo, chi, alpha_ref[8], beta_ref[8]

    const int t  = threadIdx.x;
    const int b  = blockIdx.x;
    const int rg = b / NCH;          // row group
    const int c  = b % NCH;          // m chunk

    {   // stage g chunk: [o][MC] rows, float4 linear copy
        float4*       dst = reinterpret_cast<float4*>(gs);
        const float4* src = reinterpret_cast<const float4*>(wsf + OFF_GT);
#pragma unroll
        for (int r = 0; r < OO * MC / 4 / 512; ++r) {
            const int i  = r * 512 + t;
            const int o  = i >> 8;          // / (MC/4)
            const int mi = i & 255;
            dst[i] = src[o * (NN / 4) + c * (MC / 4) + mi];
        }
    }

    // ---- per-block table build (parallel, sort-free; hidden under staging)
    if (t < (HH + 1) * OO + 2) {
        float w[HH], bb[HH], knee[HH];
#pragma unroll
        for (int h = 0; h < HH; ++h) {
            w[h]  = rW1[h];
            bb[h] = rb1[h];
            knee[h] = (w[h] != 0.f) ? (-bb[h] / w[h]) : INFINITY;
        }
        if (t >= (HH + 1) * OO) {           // 2 threads: Kp endpoints
            KpS[(t - (HH + 1) * OO) * (HH + 1)] =
                (t == (HH + 1) * OO) ? -INFINITY : INFINITY;
        } else {
            const int j = t >> 3, o = t & 7;
            if (o == 0 && j < HH) {          // 16 threads scatter knees by rank
                int r = 0;
#pragma unroll
                for (int h2 = 0; h2 < HH; ++h2)
                    r += (knee[h2] < knee[j] || (knee[h2] == knee[j] && h2 < j)) ? 1 : 0;
                KpS[1 + r] = knee[j];
            }
            float cAdd = rb2[o];
#pragma unroll
            for (int h = 0; h < HH; ++h)
                if (w[h] == 0.f) cAdd += fmaxf(bb[h], 0.f) * rW2[h * OO + o];

            float alpha = 0.f, beta = 0.f;
#pragma unroll
            for (int h = 0; h < HH; ++h) {
                int r = 0;
#pragma unroll
                for (int h2 = 0; h2 < HH; ++h2)
                    r += (knee[h2] < knee[h] || (knee[h2] == knee[h] && h2 < h)) ? 1 : 0;
                const bool active = (w[h] > 0.f) ? (r < j)
                                  : (w[h] < 0.f ? (r >= j) : false);
                if (active) {
                    alpha += w[h]  * rW2[h * OO + o];
                    beta  += bb[h] * rW2[h * OO + o];
                }
            }
            const float betaF = beta + cAdd;
            rowsS[j][o]     = alpha;
            rowsS[j][8 + o] = betaF;

            const float d00 = nd[0] / nm[0];
            int j0 = 0;
#pragma unroll
            for (int h = 0; h < HH; ++h) j0 += (d00 >= knee[h]) ? 1 : 0;
            if (j == j0) {
                refS[2 + o]  = alpha;
                refS[10 + o] = betaF;
                if (o == 0) {
                    float clo = -INFINITY, chi = INFINITY;
#pragma unroll
                    for (int h = 0; h < HH; ++h) {
                        if (d00 >= knee[h]) clo = fmaxf(clo, knee[h]);
                        else                chi = fminf(chi, knee[h]);
                    }
                    refS[0] = clo;
                    refS[1] = chi;
                }
            }
        }
    }
    __syncthreads();

    const int wave = t >> 6;
    const int lane = t & 63;

    {   // chunk g-sum: wave w sums gs[w][*] (stride-1 -> 2-way alias, free)
        float s = 0.f;
        for (int i = lane; i < MC; i += 64) s += gs[wave * MC + i];
#pragma unroll
        for (int off = 32; off > 0; off >>= 1) s += __shfl_down(s, off);
        if (lane == 0) gsum[wave] = s;
    }

    const float clo = refS[0];
    const float chi = refS[1];
    const float* refB = &refS[10];

    const int row = rg * RPB + wave;
    const float* __restrict__ drow = nd + (size_t)row * NN + c * MC;
    const float* __restrict__ nrow = nm + (size_t)row * NN + c * MC;

    float dg[OO], corr[OO];
#pragma unroll
    for (int o = 0; o < OO; ++o) { dg[o] = 0.f; corr[o] = 0.f; }

    for (int it = 0; it < MC / 256; ++it) {     // 4 iters, 4 m per lane (float4)
        const int m0 = it * 256 + lane * 4;
        const float4 dv = *reinterpret_cast<const float4*>(drow + m0);
        const float4 nv = *reinterpret_cast<const float4*>(nrow + m0);
        float4 gv[OO];
#pragma unroll
        for (int o = 0; o < OO; ++o)
            gv[o] = *reinterpret_cast<const float4*>(&gs[o * MC + m0]);

        {
            float gk[OO];
#pragma unroll
            for (int o = 0; o < OO; ++o) gk[o] = gv[o].x;
            accum_one(__fdividef(dv.x, nv.x), clo, chi, gk, dg, corr, KpS, rowsS, refB);
        }
        {
            float gk[OO];
#pragma unroll
            for (int o = 0; o < OO; ++o) gk[o] = gv[o].y;
            accum_one(__fdividef(dv.y, nv.y), clo, chi, gk, dg, corr, KpS, rowsS, refB);
        }
        {
            float gk[OO];
#pragma unroll
            for (int o = 0; o < OO; ++o) gk[o] = gv[o].z;
            accum_one(__fdividef(dv.z, nv.z), clo, chi, gk, dg, corr, KpS, rowsS, refB);
        }
        {
            float gk[OO];
#pragma unroll
            for (int o = 0; o < OO; ++o) gk[o] = gv[o].w;
            accum_one(__fdividef(dv.w, nv.w), clo, chi, gk, dg, corr, KpS, rowsS, refB);
        }
    }

    // val[o] = alpha_ref[o]*dg[o] + corr[o]; reduce over wave; atomic add
    float val[OO];
#pragma unroll
    for (int o = 0; o < OO; ++o)
        val[o] = fmaf(refS[2 + o], dg[o], corr[o]);
#pragma unroll
    for (int o = 0; o < OO; ++o) {
#pragma unroll
        for (int off = 32; off > 0; off >>= 1)
            val[o] += __shfl_down(val[o], off);
    }
    if (lane == 0) {
#pragma unroll
        for (int o = 0; o < OO; ++o)
            atomicAdd(out + (size_t)row * OO + o,
                      fmaf(refB[o], gsum[o], val[o]));
    }
}

// ---------------------------------------------------------------------------
// Host launcher — 2 dispatches total.
// Inputs: 0:x 1:edge_index(unused) 2:nd 3:nm 4:W1 5:b1 6:W2 7:b2
//         8:rW1 9:rb1 10:rW2 11:rb2
// ---------------------------------------------------------------------------
extern "C" void kernel_launch(void* const* d_in, const int* in_sizes, int n_in,
                              void* d_out, int out_size, void* d_ws, size_t ws_size,
                              hipStream_t stream) {
    const float* x   = (const float*)d_in[0];
    const float* nd  = (const float*)d_in[2];
    const float* nm  = (const float*)d_in[3];
    const float* W1  = (const float*)d_in[4];
    const float* b1  = (const float*)d_in[5];
    const float* W2  = (const float*)d_in[6];
    const float* b2  = (const float*)d_in[7];
    const float* rW1 = (const float*)d_in[8];
    const float* rb1 = (const float*)d_in[9];
    const float* rW2 = (const float*)d_in[10];
    const float* rb2 = (const float*)d_in[11];
    float* out = (float*)d_out;
    float* wsf = (float*)d_ws;

    gnan_g_kernel<<<NN / NPB, 128, 0, stream>>>(x, W1, b1, W2, b2,
                                                wsf + OFF_GT, out);
    gnan_main_kernel<<<(NN / RPB) * NCH, 512, 0, stream>>>(
        nd, nm, wsf, rW1, rb1, rW2, rb2, out);
}

// Round 7
// 163.368 us; speedup vs baseline: 1.0278x; 1.0278x over previous
//
#include <hip/hip_runtime.h>
#include <hip/hip_bf16.h>
#include <math.h>

// Problem constants: N=3072 nodes, F=128 in-feats, H=16 hidden, O=8 out
#define NN 3072
#define FF 128
#define HH 16
#define OO 8

// ws layout (float offsets): gT[O][N] only
#define OFF_GT   0

// ---------------------------------------------------------------------------
// Kernel 1: gT[o][n] = sum_f ( sum_h relu(x[n,f]*W1[f,h]+b1[f,h]) * W2[f,h,o]
//                              + b2[f,o] )
// Thread = feature, weights streamed per-h.
// ---------------------------------------------------------------------------
#define NPB 4

__global__ __launch_bounds__(128) void gnan_g_kernel(
    const float* __restrict__ x,    // [N,F]
    const float* __restrict__ W1,   // [F,H]
    const float* __restrict__ b1,   // [F,H]
    const float* __restrict__ W2,   // [F,H,O]
    const float* __restrict__ b2,   // [F,O]
    float* __restrict__ gT)         // [O][N] in ws
{
    const int f  = threadIdx.x;
    const int n0 = blockIdx.x * NPB;

    float xv[NPB];
#pragma unroll
    for (int ni = 0; ni < NPB; ++ni)
        xv[ni] = x[(size_t)(n0 + ni) * FF + f];

    const float4 b2a = *reinterpret_cast<const float4*>(b2 + f * OO);
    const float4 b2b = *reinterpret_cast<const float4*>(b2 + f * OO + 4);

    float acc[NPB][OO];
#pragma unroll
    for (int ni = 0; ni < NPB; ++ni) {
        acc[ni][0] = b2a.x; acc[ni][1] = b2a.y; acc[ni][2] = b2a.z; acc[ni][3] = b2a.w;
        acc[ni][4] = b2b.x; acc[ni][5] = b2b.y; acc[ni][6] = b2b.z; acc[ni][7] = b2b.w;
    }

    for (int h = 0; h < HH; ++h) {
        const float w1h = W1[f * HH + h];
        const float b1h = b1[f * HH + h];
        const float4 wa = *reinterpret_cast<const float4*>(W2 + (size_t)(f * HH + h) * OO);
        const float4 wb = *reinterpret_cast<const float4*>(W2 + (size_t)(f * HH + h) * OO + 4);
#pragma unroll
        for (int ni = 0; ni < NPB; ++ni) {
            const float a = fmaxf(fmaf(xv[ni], w1h, b1h), 0.f);
            acc[ni][0] = fmaf(a, wa.x, acc[ni][0]);
            acc[ni][1] = fmaf(a, wa.y, acc[ni][1]);
            acc[ni][2] = fmaf(a, wa.z, acc[ni][2]);
            acc[ni][3] = fmaf(a, wa.w, acc[ni][3]);
            acc[ni][4] = fmaf(a, wb.x, acc[ni][4]);
            acc[ni][5] = fmaf(a, wb.y, acc[ni][5]);
            acc[ni][6] = fmaf(a, wb.z, acc[ni][6]);
            acc[ni][7] = fmaf(a, wb.w, acc[ni][7]);
        }
    }

    __shared__ float wsum[NPB][2][OO];
    const int lane = threadIdx.x & 63;
    const int wid  = threadIdx.x >> 6;
#pragma unroll
    for (int ni = 0; ni < NPB; ++ni) {
#pragma unroll
        for (int o = 0; o < OO; ++o) {
#pragma unroll
            for (int off = 32; off > 0; off >>= 1)
                acc[ni][o] += __shfl_down(acc[ni][o], off);
        }
        if (lane == 0) {
#pragma unroll
            for (int o = 0; o < OO; ++o) wsum[ni][wid][o] = acc[ni][o];
        }
    }
    __syncthreads();
    if (threadIdx.x < NPB * OO) {
        const int ni = threadIdx.x >> 3, o = threadIdx.x & 7;
        gT[o * NN + (n0 + ni)] = wsum[ni][0][o] + wsum[ni][1][o];
    }
}

// ---------------------------------------------------------------------------
// Kernel 2 (main): out[n,o] = alpha_ref[o]*sum_m d*g + beta_ref[o]*sum_m g
//                             + corrections (rare, exec-masked).
// Pure streaming: NO gT LDS staging (gT is 96 KB, L2-resident -> read direct),
// no gsum phase, no atomics, no out-zeroing. Block = 256 thr = 4 waves =
// 4 rows; wave owns its row end-to-end (shuffle-reduce + direct store).
// 12 independent float4 iterations/lane give the latency-hiding ILP the
// round-6 4-iter phase-chained version lacked.
// ---------------------------------------------------------------------------
__device__ __forceinline__ void accum_one(
    float d, float clo, float chi, const float gk[OO],
    float dg[OO], float sg[OO], float corr[OO],
    const float* KpS, const float (*rowsS)[16], const float* refB)
{
#pragma unroll
    for (int o = 0; o < OO; ++o) sg[o] += gk[o];     // row-indep beta term
    if (d >= clo && d < chi) {                        // reference interval (hot)
#pragma unroll
        for (int o = 0; o < OO; ++o) dg[o] = fmaf(d, gk[o], dg[o]);
    } else {                                          // rare exact correction
        int j = 0;
#pragma unroll
        for (int p = 0; p < HH; ++p) j += (d >= KpS[1 + p]) ? 1 : 0;
#pragma unroll
        for (int o = 0; o < OO; ++o) {
            const float v = fmaf(rowsS[j][o], d, rowsS[j][8 + o]) - refB[o];
            corr[o] = fmaf(v, gk[o], corr[o]);
        }
    }
}

__global__ __launch_bounds__(256) void gnan_main_kernel(
    const float* __restrict__ nd,    // [N,N]
    const float* __restrict__ nm,    // [N,N]
    const float* __restrict__ gT,    // [O][N] in ws (L2-resident)
    const float* __restrict__ rW1,   // [H]
    const float* __restrict__ rb1,   // [H]
    const float* __restrict__ rW2,   // [H,O]
    const float* __restrict__ rb2,   // [O]
    float* __restrict__ out)         // [N,O]
{
    __shared__ float KpS[HH + 2];
    __shared__ float rowsS[HH + 1][16];
    __shared__ float refS[18];       // clo, chi, alpha_ref[8], beta_ref[8]

    const int t = threadIdx.x;

    // ---- per-block table build (parallel, sort-free; 138 threads)
    if (t < (HH + 1) * OO + 2) {
        float w[HH], bb[HH], knee[HH];
#pragma unroll
        for (int h = 0; h < HH; ++h) {
            w[h]  = rW1[h];
            bb[h] = rb1[h];
            knee[h] = (w[h] != 0.f) ? (-bb[h] / w[h]) : INFINITY;
        }
        if (t >= (HH + 1) * OO) {           // 2 threads: Kp endpoints
            KpS[(t - (HH + 1) * OO) * (HH + 1)] =
                (t == (HH + 1) * OO) ? -INFINITY : INFINITY;
        } else {
            const int j = t >> 3, o = t & 7;
            if (o == 0 && j < HH) {          // 16 threads scatter knees by rank
                int r = 0;
#pragma unroll
                for (int h2 = 0; h2 < HH; ++h2)
                    r += (knee[h2] < knee[j] || (knee[h2] == knee[j] && h2 < j)) ? 1 : 0;
                KpS[1 + r] = knee[j];
            }
            float cAdd = rb2[o];
#pragma unroll
            for (int h = 0; h < HH; ++h)
                if (w[h] == 0.f) cAdd += fmaxf(bb[h], 0.f) * rW2[h * OO + o];

            float alpha = 0.f, beta = 0.f;
#pragma unroll
            for (int h = 0; h < HH; ++h) {
                int r = 0;
#pragma unroll
                for (int h2 = 0; h2 < HH; ++h2)
                    r += (knee[h2] < knee[h] || (knee[h2] == knee[h] && h2 < h)) ? 1 : 0;
                const bool active = (w[h] > 0.f) ? (r < j)
                                  : (w[h] < 0.f ? (r >= j) : false);
                if (active) {
                    alpha += w[h]  * rW2[h * OO + o];
                    beta  += bb[h] * rW2[h * OO + o];
                }
            }
            const float betaF = beta + cAdd;
            rowsS[j][o]     = alpha;
            rowsS[j][8 + o] = betaF;

            const float d00 = nd[0] / nm[0];
            int j0 = 0;
#pragma unroll
            for (int h = 0; h < HH; ++h) j0 += (d00 >= knee[h]) ? 1 : 0;
            if (j == j0) {
                refS[2 + o]  = alpha;
                refS[10 + o] = betaF;
                if (o == 0) {
                    float clo = -INFINITY, chi = INFINITY;
#pragma unroll
                    for (int h = 0; h < HH; ++h) {
                        if (d00 >= knee[h]) clo = fmaxf(clo, knee[h]);
                        else                chi = fminf(chi, knee[h]);
                    }
                    refS[0] = clo;
                    refS[1] = chi;
                }
            }
        }
    }
    __syncthreads();

    const int wave = t >> 6;
    const int lane = t & 63;
    const int row  = blockIdx.x * 4 + wave;

    const float clo = refS[0];
    const float chi = refS[1];
    const float* refB = &refS[10];

    const float* __restrict__ drow = nd + (size_t)row * NN;
    const float* __restrict__ nrow = nm + (size_t)row * NN;

    float dg[OO], sg[OO], corr[OO];
#pragma unroll
    for (int o = 0; o < OO; ++o) { dg[o] = 0.f; sg[o] = 0.f; corr[o] = 0.f; }

    for (int it = 0; it < NN / 256; ++it) {     // 12 iters, 4 m per lane
        const int m0 = it * 256 + lane * 4;
        const float4 dv = *reinterpret_cast<const float4*>(drow + m0);
        const float4 nv = *reinterpret_cast<const float4*>(nrow + m0);
        float4 gv[OO];
#pragma unroll
        for (int o = 0; o < OO; ++o)
            gv[o] = *reinterpret_cast<const float4*>(&gT[o * NN + m0]);

        {
            float gk[OO];
#pragma unroll
            for (int o = 0; o < OO; ++o) gk[o] = gv[o].x;
            accum_one(__fdividef(dv.x, nv.x), clo, chi, gk, dg, sg, corr, KpS, rowsS, refB);
        }
        {
            float gk[OO];
#pragma unroll
            for (int o = 0; o < OO; ++o) gk[o] = gv[o].y;
            accum_one(__fdividef(dv.y, nv.y), clo, chi, gk, dg, sg, corr, KpS, rowsS, refB);
        }
        {
            float gk[OO];
#pragma unroll
            for (int o = 0; o < OO; ++o) gk[o] = gv[o].z;
            accum_one(__fdividef(dv.z, nv.z), clo, chi, gk, dg, sg, corr, KpS, rowsS, refB);
        }
        {
            float gk[OO];
#pragma unroll
            for (int o = 0; o < OO; ++o) gk[o] = gv[o].w;
            accum_one(__fdividef(dv.w, nv.w), clo, chi, gk, dg, sg, corr, KpS, rowsS, refB);
        }
    }

    // val[o] = alpha_ref*dg + beta_ref*sg + corr; wave-reduce; direct store
    float val[OO];
#pragma unroll
    for (int o = 0; o < OO; ++o)
        val[o] = fmaf(refS[2 + o], dg[o], fmaf(refB[o], sg[o], corr[o]));
#pragma unroll
    for (int o = 0; o < OO; ++o) {
#pragma unroll
        for (int off = 32; off > 0; off >>= 1)
            val[o] += __shfl_down(val[o], off);
    }
    if (lane == 0) {
#pragma unroll
        for (int o = 0; o < OO; ++o)
            out[(size_t)row * OO + o] = val[o];
    }
}

// ---------------------------------------------------------------------------
// Host launcher — 2 dispatches.
// Inputs: 0:x 1:edge_index(unused) 2:nd 3:nm 4:W1 5:b1 6:W2 7:b2
//         8:rW1 9:rb1 10:rW2 11:rb2
// ---------------------------------------------------------------------------
extern "C" void kernel_launch(void* const* d_in, const int* in_sizes, int n_in,
                              void* d_out, int out_size, void* d_ws, size_t ws_size,
                              hipStream_t stream) {
    const float* x   = (const float*)d_in[0];
    const float* nd  = (const float*)d_in[2];
    const float* nm  = (const float*)d_in[3];
    const float* W1  = (const float*)d_in[4];
    const float* b1  = (const float*)d_in[5];
    const float* W2  = (const float*)d_in[6];
    const float* b2  = (const float*)d_in[7];
    const float* rW1 = (const float*)d_in[8];
    const float* rb1 = (const float*)d_in[9];
    const float* rW2 = (const float*)d_in[10];
    const float* rb2 = (const float*)d_in[11];
    float* out = (float*)d_out;
    float* wsf = (float*)d_ws;

    gnan_g_kernel<<<NN / NPB, 128, 0, stream>>>(x, W1, b1, W2, b2, wsf + OFF_GT);
    gnan_main_kernel<<<NN / 4, 256, 0, stream>>>(
        nd, nm, wsf + OFF_GT, rW1, rb1, rW2, rb2, out);
}